// Round 10
// baseline (74.599 us; speedup 1.0000x reference)
//
#include <hip/hip_runtime.h>
#include <math.h>

// dims
#define B_    256
#define IN_   256
#define OUT_  256
#define ST_   512
#define H_    4
#define M_    64
#define N_    1024
#define D_    1024     // IN + ST + H*M
#define PPH_  198
#define UPD_  792
#define NTOT  1560     // ST + OUT + UPD
#define CP_   1600     // padded col count for GEMM partials (25*64)
#define KS_   4        // K-split factor
#define WCONV_BLKS 780 // 780*256*8 = 1,597,440 bf16 weight elements

typedef unsigned short ushort_;
typedef unsigned int uint_;

typedef __attribute__((ext_vector_type(8))) short bf16x8;
typedef __attribute__((ext_vector_type(4))) float f32x4;

__device__ __forceinline__ float sigmoidf_(float x){ return 1.f/(1.f+__expf(-x)); }
// fast softplus: fmax(x,0) + log(1+exp(-|x|)) via fast log/exp
__device__ __forceinline__ float softplusf_(float x){
    float ax = fabsf(x);
    return fmaxf(x, 0.f) + __logf(1.f + __expf(-ax));
}
// fast tanh: 1 - 2/(exp(2x)+1)
__device__ __forceinline__ float tanhf_(float x){
    return 1.f - 2.f/(__expf(2.f*x) + 1.f);
}
__device__ __forceinline__ ushort_ f2bf(float f){
    uint_ u = __float_as_uint(f);
    u += 0x7fffu + ((u >> 16) & 1u);
    return (ushort_)(u >> 16);
}

// ---------------------------------------------------------------------------
// K1 "front": fused wconv + gate + gated-wt + FULL read-einsum per batch.
// Grid: [0, B_) read blocks (one per batch, 4 waves, 1024 rows each — no
// chunk partials, no merge kernel); [B_, +WCONV_BLKS) wconv blocks.
// ---------------------------------------------------------------------------
__global__ __launch_bounds__(256) void k_front(
    const float* __restrict__ tm_input, const float* __restrict__ tm_state,
    const float* __restrict__ wt, const float* __restrict__ mem,
    const float* __restrict__ W_i2w, const float* __restrict__ b_i2w,
    const float* __restrict__ W_i2s, const float* __restrict__ W_i2o,
    const float* __restrict__ W_i2u, ushort_* __restrict__ Wb,
    float* __restrict__ wt_g, ushort_* __restrict__ cB)
{
    const int bid = blockIdx.x;
    if (bid >= B_) {
        // ---- wconv role ----
        const int idx = ((bid - B_)*256 + threadIdx.x) * 8;
        const float* src;
        if (idx < 512*1024)      src = W_i2s + idx;
        else if (idx < 768*1024) src = W_i2o + (idx - 512*1024);
        else                     src = W_i2u + (idx - 768*1024);
        float4 v0 = *(const float4*)src;
        float4 v1 = *(const float4*)(src + 4);
        union { ushort_ u[8]; uint4 q; } r;
        r.u[0]=f2bf(v0.x); r.u[1]=f2bf(v0.y); r.u[2]=f2bf(v0.z); r.u[3]=f2bf(v0.w);
        r.u[4]=f2bf(v1.x); r.u[5]=f2bf(v1.y); r.u[6]=f2bf(v1.z); r.u[7]=f2bf(v1.w);
        *(uint4*)(Wb + idx) = r.q;
        return;
    }

    // ---- read role: one block per batch ----
    __shared__ float wt_sl[N_*H_];       // [n][h] transposed, 16 KB
    __shared__ float part[4][H_][M_];    // 4 KB
    __shared__ float f_s[H_];
    const int b = bid, tid = threadIdx.x;
    const int wave = tid >> 6, lane = tid & 63;
    const float* st  = tm_state + (size_t)b*ST_;
    const float* inp = tm_input + (size_t)b*IN_;

    // gate f: wave == head
    {
        float pa = 0.f;
        const float* Wrow = W_i2w + wave*(ST_+IN_);
        #pragma unroll
        for (int k = 0; k < 12; ++k) {
            int i = lane + 64*k;
            float v = (i < ST_) ? st[i] : inp[i - ST_];
            pa += v * Wrow[i];
        }
        #pragma unroll
        for (int m = 32; m; m >>= 1) pa += __shfl_xor(pa, m, 64);
        if (lane == 0) f_s[wave] = sigmoidf_(pa + b_i2w[wave]);
    }
    // cB input/state assembly
    #pragma unroll
    for (int i = 0; i < 3; ++i) {
        int j = tid + 256*i;
        cB[(size_t)b*D_ + j] = f2bf(j < IN_ ? inp[j] : st[j - IN_]);
    }
    __syncthreads();

    // gated wt: stage full transposed batch in LDS + write wt_g
    #pragma unroll
    for (int i = 0; i < 16; ++i) {
        int idx = tid + 256*i;           // 0..4095
        int h = idx & 3, n = idx >> 2;
        float f = f_s[h];
        float v = (1.f - f) * wt[((size_t)b*H_ + h)*N_ + n];
        if (n == 0) v += f;
        wt_sl[idx] = v;
        wt_g[((size_t)b*H_ + h)*N_ + n] = v;
    }
    __syncthreads();

    // einsum: wave owns 256 contiguous rows (64 KB), all 4 heads at once
    {
        const int m4 = lane & 15, ro = lane >> 4;
        const float4* mp = (const float4*)(mem + (size_t)b*N_*M_);
        float4 a0 = make_float4(0.f,0.f,0.f,0.f), a1 = a0, a2 = a0, a3 = a0;
        #pragma unroll 8
        for (int r = 0; r < 64; ++r) {
            const int nl = wave*256 + r*4 + ro;
            const float4 mv = mp[nl*16 + m4];
            const float4 wv = *(const float4*)&wt_sl[nl*4];
            a0.x += wv.x*mv.x; a0.y += wv.x*mv.y; a0.z += wv.x*mv.z; a0.w += wv.x*mv.w;
            a1.x += wv.y*mv.x; a1.y += wv.y*mv.y; a1.z += wv.y*mv.z; a1.w += wv.y*mv.w;
            a2.x += wv.z*mv.x; a2.y += wv.z*mv.y; a2.z += wv.z*mv.z; a2.w += wv.z*mv.w;
            a3.x += wv.w*mv.x; a3.y += wv.w*mv.y; a3.z += wv.w*mv.z; a3.w += wv.w*mv.w;
        }
        #pragma unroll
        for (int msk = 16; msk <= 32; msk <<= 1) {
            a0.x += __shfl_xor(a0.x, msk, 64); a0.y += __shfl_xor(a0.y, msk, 64);
            a0.z += __shfl_xor(a0.z, msk, 64); a0.w += __shfl_xor(a0.w, msk, 64);
            a1.x += __shfl_xor(a1.x, msk, 64); a1.y += __shfl_xor(a1.y, msk, 64);
            a1.z += __shfl_xor(a1.z, msk, 64); a1.w += __shfl_xor(a1.w, msk, 64);
            a2.x += __shfl_xor(a2.x, msk, 64); a2.y += __shfl_xor(a2.y, msk, 64);
            a2.z += __shfl_xor(a2.z, msk, 64); a2.w += __shfl_xor(a2.w, msk, 64);
            a3.x += __shfl_xor(a3.x, msk, 64); a3.y += __shfl_xor(a3.y, msk, 64);
            a3.z += __shfl_xor(a3.z, msk, 64); a3.w += __shfl_xor(a3.w, msk, 64);
        }
        if (ro == 0) {
            *(float4*)&part[wave][0][m4*4] = a0;
            *(float4*)&part[wave][1][m4*4] = a1;
            *(float4*)&part[wave][2][m4*4] = a2;
            *(float4*)&part[wave][3][m4*4] = a3;
        }
    }
    __syncthreads();
    // cross-wave reduce + direct bf16 write into cB read section
    {
        const int h = tid >> 6, m = tid & 63;
        float r = part[0][h][m] + part[1][h][m] + part[2][h][m] + part[3][h][m];
        cB[(size_t)b*D_ + IN_ + ST_ + tid] = f2bf(r);
    }
}

// ---------------------------------------------------------------------------
// K2: bf16 MFMA controller GEMM, SPLIT-K partials. Grid (25, 4, KS_).
// ---------------------------------------------------------------------------
__global__ __launch_bounds__(256) void k_ctrl_gemm_mfma(
    const ushort_* __restrict__ cB, const ushort_* __restrict__ Wb,
    float* __restrict__ P)
{
    const int tid = threadIdx.x;
    const int w = tid >> 6, lane = tid & 63;
    const int wr = w >> 1, wc = w & 1;
    const int b0 = blockIdx.y * 64 + wr * 32;
    const int o0 = blockIdx.x * 64 + wc * 32;
    const int kb = blockIdx.z * (D_ / KS_);
    const int lrow = lane & 15, lk = (lane >> 4) * 8;

    const bf16x8* a0p = (const bf16x8*)(cB + (size_t)(b0 + lrow)*D_ + kb + lk);
    const bf16x8* a1p = (const bf16x8*)(cB + (size_t)(b0 + 16 + lrow)*D_ + kb + lk);
    const int oc0 = min(o0 + lrow, NTOT-1);
    const int oc1 = min(o0 + 16 + lrow, NTOT-1);
    const bf16x8* b0p = (const bf16x8*)(Wb + (size_t)oc0*D_ + kb + lk);
    const bf16x8* b1p = (const bf16x8*)(Wb + (size_t)oc1*D_ + kb + lk);

    f32x4 acc00 = {0.f,0.f,0.f,0.f}, acc01 = acc00, acc10 = acc00, acc11 = acc00;
    #pragma unroll
    for (int ks = 0; ks < (D_/KS_)/32; ++ks) {
        bf16x8 av0 = a0p[ks*4];
        bf16x8 av1 = a1p[ks*4];
        bf16x8 bv0 = b0p[ks*4];
        bf16x8 bv1 = b1p[ks*4];
        acc00 = __builtin_amdgcn_mfma_f32_16x16x32_bf16(av0, bv0, acc00, 0, 0, 0);
        acc01 = __builtin_amdgcn_mfma_f32_16x16x32_bf16(av0, bv1, acc01, 0, 0, 0);
        acc10 = __builtin_amdgcn_mfma_f32_16x16x32_bf16(av1, bv0, acc10, 0, 0, 0);
        acc11 = __builtin_amdgcn_mfma_f32_16x16x32_bf16(av1, bv1, acc11, 0, 0, 0);
    }

    // C/D layout: col=lane&15, row=(lane>>4)*4+reg
    float* Pp = P + (size_t)blockIdx.z * (B_*CP_);
    const int rsub = (lane >> 4) * 4;
    #pragma unroll
    for (int mi = 0; mi < 2; ++mi) {
        #pragma unroll
        for (int ni = 0; ni < 2; ++ni) {
            f32x4 v = (mi == 0) ? (ni == 0 ? acc00 : acc01)
                                : (ni == 0 ? acc10 : acc11);
            const int o = o0 + ni*16 + lrow;
            const int rbase = b0 + mi*16 + rsub;
            #pragma unroll
            for (int r = 0; r < 4; ++r)
                Pp[(size_t)(rbase + r)*CP_ + o] = v[r];
        }
    }
}

// ---------------------------------------------------------------------------
// K3: mem update + row norm + sim; params computed in the PROLOGUE directly
// from the split-K partials P (+ b_i2u). Grid B_*16, block 256. No fences.
// ---------------------------------------------------------------------------
__global__ __launch_bounds__(256) void k_memsim(
    const float* __restrict__ mem, const float* __restrict__ wt_g,
    const float* __restrict__ P, const float* __restrict__ b_i2u,
    float* __restrict__ mem_out, float* __restrict__ sim)
{
    __shared__ float es[H_*M_], as[H_*M_], ks[H_*M_];
    const int tid = threadIdx.x;
    const int b = blockIdx.x >> 4;
    const int chunk = blockIdx.x & 15;
    const int wave = tid >> 6, lane = tid & 63;

    // ---- params prologue: wave == head; u[j] = sum_z P[z][b][768+h*PPH+j] + bias
    {
        const int m = lane;
        const size_t pb = (size_t)b*CP_ + 768 + wave*PPH_;
        #define ULOAD(j) (P[pb+(j)] + P[(size_t)B_*CP_+pb+(j)] \
                        + P[2*(size_t)B_*CP_+pb+(j)] + P[3*(size_t)B_*CP_+pb+(j)] \
                        + b_i2u[wave*PPH_+(j)])
        float ev = sigmoidf_(ULOAD(4 + m));
        float av = tanhf_(ULOAD(68 + m));
        float kv = tanhf_(ULOAD(132 + m));
        #undef ULOAD
        float ss = kv*kv;
        #pragma unroll
        for (int msk = 32; msk; msk >>= 1) ss += __shfl_xor(ss, msk, 64);
        es[tid] = ev;
        as[tid] = av;
        ks[tid] = kv / (sqrtf(ss) + 1e-8f);
    }
    __syncthreads();

    const int q = lane & 3, rloc = lane >> 2;
    const int n = chunk*64 + wave*16 + rloc;       // row index

    const float w0 = wt_g[((size_t)b*H_ + 0)*N_ + n];
    const float w1 = wt_g[((size_t)b*H_ + 1)*N_ + n];
    const float w2 = wt_g[((size_t)b*H_ + 2)*N_ + n];
    const float w3 = wt_g[((size_t)b*H_ + 3)*N_ + n];

    const float4* mp = (const float4*)(mem     + ((size_t)b*N_ + n)*M_ + q*16);
    float4*       op = (float4*)      (mem_out + ((size_t)b*N_ + n)*M_ + q*16);

    float nrm = 0.f, p0 = 0.f, p1 = 0.f, p2 = 0.f, p3 = 0.f;
    #pragma unroll
    for (int jj = 0; jj < 4; ++jj) {
        const int c4 = q*16 + jj*4;                // column offset (floats)
        const float4 o  = mp[jj];
        const float4 e0 = *(const float4*)&es[      c4];
        const float4 e1 = *(const float4*)&es[ 64 + c4];
        const float4 e2 = *(const float4*)&es[128 + c4];
        const float4 e3 = *(const float4*)&es[192 + c4];
        const float4 a0 = *(const float4*)&as[      c4];
        const float4 a1 = *(const float4*)&as[ 64 + c4];
        const float4 a2 = *(const float4*)&as[128 + c4];
        const float4 a3 = *(const float4*)&as[192 + c4];
        const float4 k0 = *(const float4*)&ks[      c4];
        const float4 k1 = *(const float4*)&ks[ 64 + c4];
        const float4 k2 = *(const float4*)&ks[128 + c4];
        const float4 k3 = *(const float4*)&ks[192 + c4];

        float4 nm;
        nm.x = o.x*((1.f-w0*e0.x)*(1.f-w1*e1.x)*(1.f-w2*e2.x)*(1.f-w3*e3.x))
             + (w0*a0.x + w1*a1.x + w2*a2.x + w3*a3.x);
        nm.y = o.y*((1.f-w0*e0.y)*(1.f-w1*e1.y)*(1.f-w2*e2.y)*(1.f-w3*e3.y))
             + (w0*a0.y + w1*a1.y + w2*a2.y + w3*a3.y);
        nm.z = o.z*((1.f-w0*e0.z)*(1.f-w1*e1.z)*(1.f-w2*e2.z)*(1.f-w3*e3.z))
             + (w0*a0.z + w1*a1.z + w2*a2.z + w3*a3.z);
        nm.w = o.w*((1.f-w0*e0.w)*(1.f-w1*e1.w)*(1.f-w2*e2.w)*(1.f-w3*e3.w))
             + (w0*a0.w + w1*a1.w + w2*a2.w + w3*a3.w);
        op[jj] = nm;

        nrm += nm.x*nm.x + nm.y*nm.y + nm.z*nm.z + nm.w*nm.w;
        p0 += k0.x*nm.x + k0.y*nm.y + k0.z*nm.z + k0.w*nm.w;
        p1 += k1.x*nm.x + k1.y*nm.y + k1.z*nm.z + k1.w*nm.w;
        p2 += k2.x*nm.x + k2.y*nm.y + k2.z*nm.z + k2.w*nm.w;
        p3 += k3.x*nm.x + k3.y*nm.y + k3.z*nm.z + k3.w*nm.w;
    }
    #pragma unroll
    for (int msk = 1; msk <= 2; msk <<= 1) {
        nrm += __shfl_xor(nrm, msk, 64);
        p0  += __shfl_xor(p0,  msk, 64);
        p1  += __shfl_xor(p1,  msk, 64);
        p2  += __shfl_xor(p2,  msk, 64);
        p3  += __shfl_xor(p3,  msk, 64);
    }
    const float inv = 1.f/(sqrtf(nrm) + 1e-8f);
    const float pv = (q == 0) ? p0 : (q == 1) ? p1 : (q == 2) ? p2 : p3;
    sim[((size_t)b*H_ + q)*N_ + n] = pv*inv;
}

// ---------------------------------------------------------------------------
// K5: wt finalization per (b,h); scalars computed inline from P (fast math);
// also merges + activates 192 out/state columns per block as a tail.
// Grid B_*H_, block 256.
// ---------------------------------------------------------------------------
__global__ __launch_bounds__(256) void k_wt_final(
    const float* __restrict__ sim, const float* __restrict__ wt_g,
    const float* __restrict__ P,
    const float* __restrict__ b_i2s, const float* __restrict__ b_i2o,
    const float* __restrict__ b_i2u,
    float* __restrict__ out, float* __restrict__ wt_out)
{
    __shared__ float wc[N_];
    __shared__ float red[8];
    const int bh = blockIdx.x, tid = threadIdx.x, wave = tid >> 6, lane = tid & 63;
    const int b = bh >> 2, h = bh & 3;

    // ---- out/state merge tail: 192 cols per block ----
    if (tid < 192) {
        const int o = h*192 + tid;
        const size_t base = (size_t)b*CP_ + o;
        float v = P[base] + P[(size_t)B_*CP_ + base]
                + P[2*(size_t)B_*CP_ + base] + P[3*(size_t)B_*CP_ + base];
        if (o < ST_)
            out[(size_t)B_*OUT_ + (size_t)b*ST_ + o] = sigmoidf_(v + b_i2s[o]);
        else
            out[(size_t)b*OUT_ + (o - ST_)] = sigmoidf_(v + b_i2o[o - ST_]);
    }

    // ---- scalar params from P (fast softplus/exp; uniform per block) ----
    const size_t pb = (size_t)b*CP_ + 768 + h*PPH_;
    #define ULOAD(j) (P[pb+(j)] + P[(size_t)B_*CP_+pb+(j)] \
                    + P[2*(size_t)B_*CP_+pb+(j)] + P[3*(size_t)B_*CP_+pb+(j)] \
                    + b_i2u[h*PPH_+(j)])
    const float sp0 = softplusf_(ULOAD(0));
    const float sp1 = softplusf_(ULOAD(1));
    const float sp2 = softplusf_(ULOAD(2));
    const float gamma = 1.f + softplusf_(ULOAD(3));
    const float beta  = softplusf_(ULOAD(196));
    const float g     = sigmoidf_(ULOAD(197));
    #undef ULOAD
    const float mx3 = fmaxf(sp0, fmaxf(sp1, sp2));
    const float ee0 = __expf(sp0-mx3), ee1 = __expf(sp1-mx3), ee2 = __expf(sp2-mx3);
    const float inv3 = 1.f/(ee0+ee1+ee2);
    const float s0 = ee0*inv3, s1 = ee1*inv3, s2 = ee2*inv3;

    const float* simp = sim + (size_t)bh*N_;
    const float* wgp  = wt_g + (size_t)bh*N_;

    float x[4];
    float mx = -1e30f;
    #pragma unroll
    for (int i = 0; i < 4; ++i) { x[i] = beta*simp[tid + 256*i]; mx = fmaxf(mx, x[i]); }
    #pragma unroll
    for (int msk = 32; msk; msk >>= 1) mx = fmaxf(mx, __shfl_xor(mx, msk, 64));
    if (lane == 0) red[wave] = mx;
    __syncthreads();
    mx = fmaxf(fmaxf(red[0], red[1]), fmaxf(red[2], red[3]));

    float e[4]; float sum = 0.f;
    #pragma unroll
    for (int i = 0; i < 4; ++i) { e[i] = __expf(x[i] - mx); sum += e[i]; }
    #pragma unroll
    for (int msk = 32; msk; msk >>= 1) sum += __shfl_xor(sum, msk, 64);
    if (lane == 0) red[4 + wave] = sum;
    __syncthreads();
    sum = red[4] + red[5] + red[6] + red[7];
    const float inv = 1.f/sum;

    #pragma unroll
    for (int i = 0; i < 4; ++i) {
        int n = tid + 256*i;
        wc[n] = g*e[i]*inv + (1.f - g)*wgp[n];
    }
    __syncthreads();

    // v > 0 always (wc >= 0, shift weights >= 0, +1e-12), so pow via exp/log
    float y[4]; float ysum = 0.f;
    #pragma unroll
    for (int i = 0; i < 4; ++i) {
        int n = tid + 256*i;
        float v = s0*wc[(n+1) & (N_-1)] + s1*wc[n] + s2*wc[(n-1) & (N_-1)];
        y[i] = __expf(gamma * __logf(v + 1e-12f));
        ysum += y[i];
    }
    #pragma unroll
    for (int msk = 32; msk; msk >>= 1) ysum += __shfl_xor(ysum, msk, 64);
    __syncthreads();
    if (lane == 0) red[wave] = ysum;
    __syncthreads();
    ysum = red[0] + red[1] + red[2] + red[3];
    const float yinv = 1.f/ysum;
    #pragma unroll
    for (int i = 0; i < 4; ++i)
        wt_out[(size_t)bh*N_ + tid + 256*i] = y[i]*yinv;
}

// ---------------------------------------------------------------------------
extern "C" void kernel_launch(void* const* d_in, const int* in_sizes, int n_in,
                              void* d_out, int out_size, void* d_ws, size_t ws_size,
                              hipStream_t stream)
{
    const float* tm_input = (const float*)d_in[0];
    const float* tm_state = (const float*)d_in[1];
    const float* wt       = (const float*)d_in[2];
    const float* mem      = (const float*)d_in[3];
    const float* W_i2w    = (const float*)d_in[4];
    const float* b_i2w    = (const float*)d_in[5];
    const float* W_i2s    = (const float*)d_in[6];
    const float* b_i2s    = (const float*)d_in[7];
    const float* W_i2o    = (const float*)d_in[8];
    const float* b_i2o    = (const float*)d_in[9];
    const float* W_i2u    = (const float*)d_in[10];
    const float* b_i2u    = (const float*)d_in[11];

    float* out = (float*)d_out;
    float* ws  = (float*)d_ws;

    // ws layout (float offsets; all 16B aligned)
    float*   wt_g  = ws;                       // 1,048,576 f
    ushort_* cB    = (ushort_*)(ws + 1048576); //   262,144 bf16 (131,072 f)
    ushort_* Wb    = (ushort_*)(ws + 1179648); // 1,597,440 bf16 (798,720 f)
    float*   P     = ws + 1978368;             // KS_*B_*CP_ = 1,638,400 f
    float*   simb  = ws + 3616768;             // 1,048,576 f -> ~17.9 MB total

    // out layout (floats): tm_output[0], state[65536], wt[196608], mem[1245184]
    float* out_wt  = out + 196608;
    float* out_mem = out + 1245184;

    hipLaunchKernelGGL(k_front, dim3(B_ + WCONV_BLKS), dim3(256), 0, stream,
                       tm_input, tm_state, wt, mem, W_i2w, b_i2w,
                       W_i2s, W_i2o, W_i2u, Wb, wt_g, cB);
    hipLaunchKernelGGL(k_ctrl_gemm_mfma, dim3(25, 4, KS_), dim3(256), 0, stream,
                       cB, Wb, P);
    hipLaunchKernelGGL(k_memsim, dim3(B_*16), dim3(256), 0, stream,
                       mem, wt_g, P, b_i2u, out_mem, simb);
    hipLaunchKernelGGL(k_wt_final, dim3(B_*H_), dim3(256), 0, stream,
                       simb, wt_g, P, b_i2s, b_i2o, b_i2u, out, out_wt);
}

// Round 11
// 70.127 us; speedup vs baseline: 1.0638x; 1.0638x over previous
//
#include <hip/hip_runtime.h>
#include <math.h>

// dims
#define B_    256
#define IN_   256
#define OUT_  256
#define ST_   512
#define H_    4
#define M_    64
#define N_    1024
#define D_    1024     // IN + ST + H*M
#define PPH_  198
#define UPD_  792
#define NTOT  1560     // ST + OUT + UPD
#define CP_   1600     // padded col count for GEMM partials (25*64)
#define KS_   4        // K-split factor
#define RCH_  8        // read-einsum chunks per batch (128 rows each)
#define WCONV_BLKS 780 // 780*256*8 = 1,597,440 bf16 weight elements

typedef unsigned short ushort_;
typedef unsigned int uint_;

typedef __attribute__((ext_vector_type(8))) short bf16x8;
typedef __attribute__((ext_vector_type(4))) float f32x4;

__device__ __forceinline__ float sigmoidf_(float x){ return 1.f/(1.f+__expf(-x)); }
// fast softplus: fmax(x,0) + log(1+exp(-|x|)) via fast log/exp
__device__ __forceinline__ float softplusf_(float x){
    float ax = fabsf(x);
    return fmaxf(x, 0.f) + __logf(1.f + __expf(-ax));
}
// fast tanh: 1 - 2/(exp(2x)+1)
__device__ __forceinline__ float tanhf_(float x){
    return 1.f - 2.f/(__expf(2.f*x) + 1.f);
}
__device__ __forceinline__ ushort_ f2bf(float f){
    uint_ u = __float_as_uint(f);
    u += 0x7fffu + ((u >> 16) & 1u);
    return (ushort_)(u >> 16);
}

// ---------------------------------------------------------------------------
// K1 "front": fused wconv + gate + gated-wt + read-einsum partials.
// Grid: [0, B_*RCH_) read blocks (b = bid>>3, chunk = bid&7, 128 rows each);
//       [B_*RCH_, +WCONV_BLKS) wconv blocks.
// RCH=8 -> 2048 read blocks = 8 blocks/CU = 32 waves/CU sustained (100% occ)
// during the 64 MB mem stream (round-10 lesson: stream rate ~ occupancy).
// ---------------------------------------------------------------------------
__global__ __launch_bounds__(256) void k_front(
    const float* __restrict__ tm_input, const float* __restrict__ tm_state,
    const float* __restrict__ wt, const float* __restrict__ mem,
    const float* __restrict__ W_i2w, const float* __restrict__ b_i2w,
    const float* __restrict__ W_i2s, const float* __restrict__ W_i2o,
    const float* __restrict__ W_i2u, ushort_* __restrict__ Wb,
    float* __restrict__ wt_g, ushort_* __restrict__ cB,
    float* __restrict__ Pr)
{
    const int bid = blockIdx.x;
    if (bid >= B_*RCH_) {
        // ---- wconv role ----
        const int idx = ((bid - B_*RCH_)*256 + threadIdx.x) * 8;
        const float* src;
        if (idx < 512*1024)      src = W_i2s + idx;
        else if (idx < 768*1024) src = W_i2o + (idx - 512*1024);
        else                     src = W_i2u + (idx - 768*1024);
        float4 v0 = *(const float4*)src;
        float4 v1 = *(const float4*)(src + 4);
        union { ushort_ u[8]; uint4 q; } r;
        r.u[0]=f2bf(v0.x); r.u[1]=f2bf(v0.y); r.u[2]=f2bf(v0.z); r.u[3]=f2bf(v0.w);
        r.u[4]=f2bf(v1.x); r.u[5]=f2bf(v1.y); r.u[6]=f2bf(v1.z); r.u[7]=f2bf(v1.w);
        *(uint4*)(Wb + idx) = r.q;
        return;
    }

    // ---- read role ----
    __shared__ float wt_sl[128*H_];      // [n_local][h], 2 KB
    __shared__ float part[4][H_][M_];    // 4 KB
    __shared__ float f_s[H_];
    const int b = bid >> 3, chunk = bid & 7, tid = threadIdx.x;
    const int wave = tid >> 6, lane = tid & 63;
    const float* st  = tm_state + (size_t)b*ST_;
    const float* inp = tm_input + (size_t)b*IN_;

    // gate f: wave == head
    {
        float pa = 0.f;
        const float* Wrow = W_i2w + wave*(ST_+IN_);
        #pragma unroll
        for (int k = 0; k < 12; ++k) {
            int i = lane + 64*k;
            float v = (i < ST_) ? st[i] : inp[i - ST_];
            pa += v * Wrow[i];
        }
        #pragma unroll
        for (int m = 32; m; m >>= 1) pa += __shfl_xor(pa, m, 64);
        if (lane == 0) f_s[wave] = sigmoidf_(pa + b_i2w[wave]);
    }
    // cB input/state assembly (once per batch: chunk 0 only)
    if (chunk == 0) {
        #pragma unroll
        for (int i = 0; i < 3; ++i) {
            int j = tid + 256*i;
            cB[(size_t)b*D_ + j] = f2bf(j < IN_ ? inp[j] : st[j - IN_]);
        }
    }
    __syncthreads();

    // gated wt: stage transposed slice in LDS + write wt_g (512 entries)
    const int nbase = chunk * 128;
    #pragma unroll
    for (int i = 0; i < 2; ++i) {
        int idx = tid + 256*i;           // 0..511
        int h = idx & 3, nl = idx >> 2;
        int n = nbase + nl;
        float f = f_s[h];
        float v = (1.f - f) * wt[((size_t)b*H_ + h)*N_ + n];
        if (n == 0) v += f;
        wt_sl[idx] = v;
        wt_g[((size_t)b*H_ + h)*N_ + n] = v;
    }
    __syncthreads();

    // einsum: wave owns 32 contiguous rows (8 KB), all 4 heads at once
    {
        const int m4 = lane & 15, ro = lane >> 4;
        const float4* mp = (const float4*)(mem + ((size_t)b*N_ + nbase)*M_);
        float4 a0 = make_float4(0.f,0.f,0.f,0.f), a1 = a0, a2 = a0, a3 = a0;
        #pragma unroll
        for (int r = 0; r < 8; ++r) {
            const int nl = wave*32 + r*4 + ro;
            const float4 mv = mp[nl*16 + m4];
            const float4 wv = *(const float4*)&wt_sl[nl*4];
            a0.x += wv.x*mv.x; a0.y += wv.x*mv.y; a0.z += wv.x*mv.z; a0.w += wv.x*mv.w;
            a1.x += wv.y*mv.x; a1.y += wv.y*mv.y; a1.z += wv.y*mv.z; a1.w += wv.y*mv.w;
            a2.x += wv.z*mv.x; a2.y += wv.z*mv.y; a2.z += wv.z*mv.z; a2.w += wv.z*mv.w;
            a3.x += wv.w*mv.x; a3.y += wv.w*mv.y; a3.z += wv.w*mv.z; a3.w += wv.w*mv.w;
        }
        #pragma unroll
        for (int msk = 16; msk <= 32; msk <<= 1) {
            a0.x += __shfl_xor(a0.x, msk, 64); a0.y += __shfl_xor(a0.y, msk, 64);
            a0.z += __shfl_xor(a0.z, msk, 64); a0.w += __shfl_xor(a0.w, msk, 64);
            a1.x += __shfl_xor(a1.x, msk, 64); a1.y += __shfl_xor(a1.y, msk, 64);
            a1.z += __shfl_xor(a1.z, msk, 64); a1.w += __shfl_xor(a1.w, msk, 64);
            a2.x += __shfl_xor(a2.x, msk, 64); a2.y += __shfl_xor(a2.y, msk, 64);
            a2.z += __shfl_xor(a2.z, msk, 64); a2.w += __shfl_xor(a2.w, msk, 64);
            a3.x += __shfl_xor(a3.x, msk, 64); a3.y += __shfl_xor(a3.y, msk, 64);
            a3.z += __shfl_xor(a3.z, msk, 64); a3.w += __shfl_xor(a3.w, msk, 64);
        }
        if (ro == 0) {
            *(float4*)&part[wave][0][m4*4] = a0;
            *(float4*)&part[wave][1][m4*4] = a1;
            *(float4*)&part[wave][2][m4*4] = a2;
            *(float4*)&part[wave][3][m4*4] = a3;
        }
    }
    __syncthreads();
    {
        const int h = tid >> 6, m = tid & 63;
        float r = part[0][h][m] + part[1][h][m] + part[2][h][m] + part[3][h][m];
        Pr[((size_t)(b*RCH_ + chunk))*256 + tid] = r;
    }
}

// ---------------------------------------------------------------------------
// K1c: merge read partials -> cB read section (bf16). Grid B_, block 256.
// ---------------------------------------------------------------------------
__global__ __launch_bounds__(256) void k_read_merge(
    const float* __restrict__ Pr, ushort_* __restrict__ cB)
{
    const int b = blockIdx.x, tid = threadIdx.x;
    float r = 0.f;
    #pragma unroll
    for (int c = 0; c < RCH_; ++c)
        r += Pr[((size_t)(b*RCH_ + c))*256 + tid];
    cB[(size_t)b*D_ + IN_ + ST_ + tid] = f2bf(r);
}

// ---------------------------------------------------------------------------
// K2: bf16 MFMA controller GEMM, SPLIT-K partials. Grid (25, 4, KS_).
// ---------------------------------------------------------------------------
__global__ __launch_bounds__(256) void k_ctrl_gemm_mfma(
    const ushort_* __restrict__ cB, const ushort_* __restrict__ Wb,
    float* __restrict__ P)
{
    const int tid = threadIdx.x;
    const int w = tid >> 6, lane = tid & 63;
    const int wr = w >> 1, wc = w & 1;
    const int b0 = blockIdx.y * 64 + wr * 32;
    const int o0 = blockIdx.x * 64 + wc * 32;
    const int kb = blockIdx.z * (D_ / KS_);
    const int lrow = lane & 15, lk = (lane >> 4) * 8;

    const bf16x8* a0p = (const bf16x8*)(cB + (size_t)(b0 + lrow)*D_ + kb + lk);
    const bf16x8* a1p = (const bf16x8*)(cB + (size_t)(b0 + 16 + lrow)*D_ + kb + lk);
    const int oc0 = min(o0 + lrow, NTOT-1);
    const int oc1 = min(o0 + 16 + lrow, NTOT-1);
    const bf16x8* b0p = (const bf16x8*)(Wb + (size_t)oc0*D_ + kb + lk);
    const bf16x8* b1p = (const bf16x8*)(Wb + (size_t)oc1*D_ + kb + lk);

    f32x4 acc00 = {0.f,0.f,0.f,0.f}, acc01 = acc00, acc10 = acc00, acc11 = acc00;
    #pragma unroll
    for (int ks = 0; ks < (D_/KS_)/32; ++ks) {
        bf16x8 av0 = a0p[ks*4];
        bf16x8 av1 = a1p[ks*4];
        bf16x8 bv0 = b0p[ks*4];
        bf16x8 bv1 = b1p[ks*4];
        acc00 = __builtin_amdgcn_mfma_f32_16x16x32_bf16(av0, bv0, acc00, 0, 0, 0);
        acc01 = __builtin_amdgcn_mfma_f32_16x16x32_bf16(av0, bv1, acc01, 0, 0, 0);
        acc10 = __builtin_amdgcn_mfma_f32_16x16x32_bf16(av1, bv0, acc10, 0, 0, 0);
        acc11 = __builtin_amdgcn_mfma_f32_16x16x32_bf16(av1, bv1, acc11, 0, 0, 0);
    }

    // C/D layout: col=lane&15, row=(lane>>4)*4+reg
    float* Pp = P + (size_t)blockIdx.z * (B_*CP_);
    const int rsub = (lane >> 4) * 4;
    #pragma unroll
    for (int mi = 0; mi < 2; ++mi) {
        #pragma unroll
        for (int ni = 0; ni < 2; ++ni) {
            f32x4 v = (mi == 0) ? (ni == 0 ? acc00 : acc01)
                                : (ni == 0 ? acc10 : acc11);
            const int o = o0 + ni*16 + lrow;
            const int rbase = b0 + mi*16 + rsub;
            #pragma unroll
            for (int r = 0; r < 4; ++r)
                Pp[(size_t)(rbase + r)*CP_ + o] = v[r];
        }
    }
}

// ---------------------------------------------------------------------------
// K3: mem update + row norm + sim; params computed in the PROLOGUE directly
// from the split-K partials P (+ b_i2u). Grid B_*16, block 256. No fences.
// ---------------------------------------------------------------------------
__global__ __launch_bounds__(256) void k_memsim(
    const float* __restrict__ mem, const float* __restrict__ wt_g,
    const float* __restrict__ P, const float* __restrict__ b_i2u,
    float* __restrict__ mem_out, float* __restrict__ sim)
{
    __shared__ float es[H_*M_], as[H_*M_], ks[H_*M_];
    const int tid = threadIdx.x;
    const int b = blockIdx.x >> 4;
    const int chunk = blockIdx.x & 15;
    const int wave = tid >> 6, lane = tid & 63;

    // ---- params prologue: wave == head; u[j] = sum_z P[z][b][768+h*PPH+j] + bias
    {
        const int m = lane;
        const size_t pb = (size_t)b*CP_ + 768 + wave*PPH_;
        #define ULOAD(j) (P[pb+(j)] + P[(size_t)B_*CP_+pb+(j)] \
                        + P[2*(size_t)B_*CP_+pb+(j)] + P[3*(size_t)B_*CP_+pb+(j)] \
                        + b_i2u[wave*PPH_+(j)])
        float ev = sigmoidf_(ULOAD(4 + m));
        float av = tanhf_(ULOAD(68 + m));
        float kv = tanhf_(ULOAD(132 + m));
        #undef ULOAD
        float ss = kv*kv;
        #pragma unroll
        for (int msk = 32; msk; msk >>= 1) ss += __shfl_xor(ss, msk, 64);
        es[tid] = ev;
        as[tid] = av;
        ks[tid] = kv / (sqrtf(ss) + 1e-8f);
    }
    __syncthreads();

    const int q = lane & 3, rloc = lane >> 2;
    const int n = chunk*64 + wave*16 + rloc;       // row index

    const float w0 = wt_g[((size_t)b*H_ + 0)*N_ + n];
    const float w1 = wt_g[((size_t)b*H_ + 1)*N_ + n];
    const float w2 = wt_g[((size_t)b*H_ + 2)*N_ + n];
    const float w3 = wt_g[((size_t)b*H_ + 3)*N_ + n];

    const float4* mp = (const float4*)(mem     + ((size_t)b*N_ + n)*M_ + q*16);
    float4*       op = (float4*)      (mem_out + ((size_t)b*N_ + n)*M_ + q*16);

    float nrm = 0.f, p0 = 0.f, p1 = 0.f, p2 = 0.f, p3 = 0.f;
    #pragma unroll
    for (int jj = 0; jj < 4; ++jj) {
        const int c4 = q*16 + jj*4;                // column offset (floats)
        const float4 o  = mp[jj];
        const float4 e0 = *(const float4*)&es[      c4];
        const float4 e1 = *(const float4*)&es[ 64 + c4];
        const float4 e2 = *(const float4*)&es[128 + c4];
        const float4 e3 = *(const float4*)&es[192 + c4];
        const float4 a0 = *(const float4*)&as[      c4];
        const float4 a1 = *(const float4*)&as[ 64 + c4];
        const float4 a2 = *(const float4*)&as[128 + c4];
        const float4 a3 = *(const float4*)&as[192 + c4];
        const float4 k0 = *(const float4*)&ks[      c4];
        const float4 k1 = *(const float4*)&ks[ 64 + c4];
        const float4 k2 = *(const float4*)&ks[128 + c4];
        const float4 k3 = *(const float4*)&ks[192 + c4];

        float4 nm;
        nm.x = o.x*((1.f-w0*e0.x)*(1.f-w1*e1.x)*(1.f-w2*e2.x)*(1.f-w3*e3.x))
             + (w0*a0.x + w1*a1.x + w2*a2.x + w3*a3.x);
        nm.y = o.y*((1.f-w0*e0.y)*(1.f-w1*e1.y)*(1.f-w2*e2.y)*(1.f-w3*e3.y))
             + (w0*a0.y + w1*a1.y + w2*a2.y + w3*a3.y);
        nm.z = o.z*((1.f-w0*e0.z)*(1.f-w1*e1.z)*(1.f-w2*e2.z)*(1.f-w3*e3.z))
             + (w0*a0.z + w1*a1.z + w2*a2.z + w3*a3.z);
        nm.w = o.w*((1.f-w0*e0.w)*(1.f-w1*e1.w)*(1.f-w2*e2.w)*(1.f-w3*e3.w))
             + (w0*a0.w + w1*a1.w + w2*a2.w + w3*a3.w);
        op[jj] = nm;

        nrm += nm.x*nm.x + nm.y*nm.y + nm.z*nm.z + nm.w*nm.w;
        p0 += k0.x*nm.x + k0.y*nm.y + k0.z*nm.z + k0.w*nm.w;
        p1 += k1.x*nm.x + k1.y*nm.y + k1.z*nm.z + k1.w*nm.w;
        p2 += k2.x*nm.x + k2.y*nm.y + k2.z*nm.z + k2.w*nm.w;
        p3 += k3.x*nm.x + k3.y*nm.y + k3.z*nm.z + k3.w*nm.w;
    }
    #pragma unroll
    for (int msk = 1; msk <= 2; msk <<= 1) {
        nrm += __shfl_xor(nrm, msk, 64);
        p0  += __shfl_xor(p0,  msk, 64);
        p1  += __shfl_xor(p1,  msk, 64);
        p2  += __shfl_xor(p2,  msk, 64);
        p3  += __shfl_xor(p3,  msk, 64);
    }
    const float inv = 1.f/(sqrtf(nrm) + 1e-8f);
    const float pv = (q == 0) ? p0 : (q == 1) ? p1 : (q == 2) ? p2 : p3;
    sim[((size_t)b*H_ + q)*N_ + n] = pv*inv;
}

// ---------------------------------------------------------------------------
// K5: wt finalization per (b,h); scalars computed inline from P (fast math);
// also merges + activates 192 out/state columns per block as a tail.
// Grid B_*H_, block 256.
// ---------------------------------------------------------------------------
__global__ __launch_bounds__(256) void k_wt_final(
    const float* __restrict__ sim, const float* __restrict__ wt_g,
    const float* __restrict__ P,
    const float* __restrict__ b_i2s, const float* __restrict__ b_i2o,
    const float* __restrict__ b_i2u,
    float* __restrict__ out, float* __restrict__ wt_out)
{
    __shared__ float wc[N_];
    __shared__ float red[8];
    const int bh = blockIdx.x, tid = threadIdx.x, wave = tid >> 6, lane = tid & 63;
    const int b = bh >> 2, h = bh & 3;

    // ---- out/state merge tail: 192 cols per block ----
    if (tid < 192) {
        const int o = h*192 + tid;
        const size_t base = (size_t)b*CP_ + o;
        float v = P[base] + P[(size_t)B_*CP_ + base]
                + P[2*(size_t)B_*CP_ + base] + P[3*(size_t)B_*CP_ + base];
        if (o < ST_)
            out[(size_t)B_*OUT_ + (size_t)b*ST_ + o] = sigmoidf_(v + b_i2s[o]);
        else
            out[(size_t)b*OUT_ + (o - ST_)] = sigmoidf_(v + b_i2o[o - ST_]);
    }

    // ---- scalar params from P (fast softplus/exp; uniform per block) ----
    const size_t pb = (size_t)b*CP_ + 768 + h*PPH_;
    #define ULOAD(j) (P[pb+(j)] + P[(size_t)B_*CP_+pb+(j)] \
                    + P[2*(size_t)B_*CP_+pb+(j)] + P[3*(size_t)B_*CP_+pb+(j)] \
                    + b_i2u[h*PPH_+(j)])
    const float sp0 = softplusf_(ULOAD(0));
    const float sp1 = softplusf_(ULOAD(1));
    const float sp2 = softplusf_(ULOAD(2));
    const float gamma = 1.f + softplusf_(ULOAD(3));
    const float beta  = softplusf_(ULOAD(196));
    const float g     = sigmoidf_(ULOAD(197));
    #undef ULOAD
    const float mx3 = fmaxf(sp0, fmaxf(sp1, sp2));
    const float ee0 = __expf(sp0-mx3), ee1 = __expf(sp1-mx3), ee2 = __expf(sp2-mx3);
    const float inv3 = 1.f/(ee0+ee1+ee2);
    const float s0 = ee0*inv3, s1 = ee1*inv3, s2 = ee2*inv3;

    const float* simp = sim + (size_t)bh*N_;
    const float* wgp  = wt_g + (size_t)bh*N_;

    float x[4];
    float mx = -1e30f;
    #pragma unroll
    for (int i = 0; i < 4; ++i) { x[i] = beta*simp[tid + 256*i]; mx = fmaxf(mx, x[i]); }
    #pragma unroll
    for (int msk = 32; msk; msk >>= 1) mx = fmaxf(mx, __shfl_xor(mx, msk, 64));
    if (lane == 0) red[wave] = mx;
    __syncthreads();
    mx = fmaxf(fmaxf(red[0], red[1]), fmaxf(red[2], red[3]));

    float e[4]; float sum = 0.f;
    #pragma unroll
    for (int i = 0; i < 4; ++i) { e[i] = __expf(x[i] - mx); sum += e[i]; }
    #pragma unroll
    for (int msk = 32; msk; msk >>= 1) sum += __shfl_xor(sum, msk, 64);
    if (lane == 0) red[4 + wave] = sum;
    __syncthreads();
    sum = red[4] + red[5] + red[6] + red[7];
    const float inv = 1.f/sum;

    #pragma unroll
    for (int i = 0; i < 4; ++i) {
        int n = tid + 256*i;
        wc[n] = g*e[i]*inv + (1.f - g)*wgp[n];
    }
    __syncthreads();

    // v > 0 always (wc >= 0, shift weights >= 0, +1e-12), so pow via exp/log
    float y[4]; float ysum = 0.f;
    #pragma unroll
    for (int i = 0; i < 4; ++i) {
        int n = tid + 256*i;
        float v = s0*wc[(n+1) & (N_-1)] + s1*wc[n] + s2*wc[(n-1) & (N_-1)];
        y[i] = __expf(gamma * __logf(v + 1e-12f));
        ysum += y[i];
    }
    #pragma unroll
    for (int msk = 32; msk; msk >>= 1) ysum += __shfl_xor(ysum, msk, 64);
    __syncthreads();
    if (lane == 0) red[wave] = ysum;
    __syncthreads();
    ysum = red[0] + red[1] + red[2] + red[3];
    const float yinv = 1.f/ysum;
    #pragma unroll
    for (int i = 0; i < 4; ++i)
        wt_out[(size_t)bh*N_ + tid + 256*i] = y[i]*yinv;
}

// ---------------------------------------------------------------------------
extern "C" void kernel_launch(void* const* d_in, const int* in_sizes, int n_in,
                              void* d_out, int out_size, void* d_ws, size_t ws_size,
                              hipStream_t stream)
{
    const float* tm_input = (const float*)d_in[0];
    const float* tm_state = (const float*)d_in[1];
    const float* wt       = (const float*)d_in[2];
    const float* mem      = (const float*)d_in[3];
    const float* W_i2w    = (const float*)d_in[4];
    const float* b_i2w    = (const float*)d_in[5];
    const float* W_i2s    = (const float*)d_in[6];
    const float* b_i2s    = (const float*)d_in[7];
    const float* W_i2o    = (const float*)d_in[8];
    const float* b_i2o    = (const float*)d_in[9];
    const float* W_i2u    = (const float*)d_in[10];
    const float* b_i2u    = (const float*)d_in[11];

    float* out = (float*)d_out;
    float* ws  = (float*)d_ws;

    // ws layout (float offsets; all 16B aligned)
    float*   wt_g  = ws;                       // 1,048,576 f
    ushort_* cB    = (ushort_*)(ws + 1048576); //   262,144 bf16 (131,072 f)
    ushort_* Wb    = (ushort_*)(ws + 1179648); // 1,597,440 bf16 (798,720 f)
    float*   P     = ws + 1978368;             // KS_*B_*CP_ = 1,638,400 f
    float*   Pr    = ws + 3616768;             // B_*RCH_*256 = 524,288 f
    float*   simb  = ws + 4141056;             // 1,048,576 f -> ~19.9 MB total

    // out layout (floats): tm_output[0], state[65536], wt[196608], mem[1245184]
    float* out_wt  = out + 196608;
    float* out_mem = out + 1245184;

    hipLaunchKernelGGL(k_front, dim3(B_*RCH_ + WCONV_BLKS), dim3(256), 0, stream,
                       tm_input, tm_state, wt, mem, W_i2w, b_i2w,
                       W_i2s, W_i2o, W_i2u, Wb, wt_g, cB, Pr);
    hipLaunchKernelGGL(k_read_merge, dim3(B_), dim3(256), 0, stream,
                       Pr, cB);
    hipLaunchKernelGGL(k_ctrl_gemm_mfma, dim3(25, 4, KS_), dim3(256), 0, stream,
                       cB, Wb, P);
    hipLaunchKernelGGL(k_memsim, dim3(B_*16), dim3(256), 0, stream,
                       mem, wt_g, P, b_i2u, out_mem, simb);
    hipLaunchKernelGGL(k_wt_final, dim3(B_*H_), dim3(256), 0, stream,
                       simb, wt_g, P, b_i2s, b_i2o, b_i2u, out, out_wt);
}